// Round 4
// baseline (62.200 us; speedup 1.0000x reference)
//
#include <hip/hip_runtime.h>
#include <math.h>

namespace {
constexpr int Qn  = 300;
constexpr int Cn  = 80;
constexpr int QC  = Qn * Cn;     // 24000 per row
constexpr int QC4 = QC / 4;      // 6000 float4 per row
constexpr int Kk  = 300;         // top-k
constexpr int NT  = 512;         // 8 waves per block
constexpr int NW  = NT / 64;     // waves per block
constexpr int CAP = 1024;        // candidate buffer capacity
constexpr int NB  = 512;         // fallback radix bins
constexpr int NBB = 2048;        // counting-sort bins

// Fast-path pre-filter: logits ~ N(0,1); K-th of 24000 sits at z ~= 2.24.
// Count(logit > 2.0) ~= 546 +- 23 => P(<300) and P(>1024) are ~0.
// Exactness for ANY input preserved by the radix-select fallback.
constexpr float T0 = 2.0f;

typedef float __attribute__((ext_vector_type(4))) f32x4;

// Non-temporal streaming load: logits are use-once data; skip cache
// allocation on the read path (emits global_load_dwordx4 ... nt).
__device__ __forceinline__ float4 ntload4(const float4* __restrict__ p) {
    const f32x4 t = __builtin_nontemporal_load((const f32x4*)p);
    return make_float4(t.x, t.y, t.z, t.w);
}

__device__ __forceinline__ unsigned mono(float f) {
    // branchless order-preserving map: b ^ ((b>>31 signed) | 0x80000000)
    unsigned b = __float_as_uint(f);
    return b ^ (unsigned)(((int)b >> 31) | (int)0x80000000);
}
__device__ __forceinline__ float inv_mono(unsigned u) {
    unsigned b = (u & 0x80000000u) ? (u & 0x7fffffffu) : ~u;
    return __uint_as_float(b);
}
// Monotone logit -> bin map (bins of width 1/512 logit above T0; clamped).
// Same-bin ties are resolved exactly by the in-group 64-bit compare.
__device__ __forceinline__ unsigned binOf(float logit) {
    int d = (int)((logit - T0) * 512.0f);
    d = d < 0 ? 0 : (d > NBB - 1 ? NBB - 1 : d);
    return (unsigned)d;
}

// Wave-0 suffix-select over NB=512 plain bins (descending). Fallback only.
__device__ __forceinline__ void select512p(const unsigned* __restrict__ h,
                                           unsigned Krem, unsigned* sT,
                                           unsigned* sGt, unsigned* sBc, int tid) {
    if (tid < 64) {
        const int base = NB - 8 * (tid + 1);   // lane 0 owns the TOP 8 bins
        const uint4 qa = *(const uint4*)&h[base + 0];
        const uint4 qb = *(const uint4*)&h[base + 4];
        const unsigned hh[8] = {qa.x, qa.y, qa.z, qa.w, qb.x, qb.y, qb.z, qb.w};
        unsigned s = 0;
        #pragma unroll
        for (int j = 0; j < 8; ++j) s += hh[j];
        unsigned inc = s;
        #pragma unroll
        for (int off = 1; off < 64; off <<= 1) {
            const unsigned n = __shfl_up(inc, off, 64);
            if (tid >= off) inc += n;
        }
        const unsigned excl = inc - s;
        if (excl < Krem && Krem <= inc) {      // exactly one lane true
            unsigned acc = excl, T = 0, bc = 0;
            bool done = false;
            #pragma unroll
            for (int j = 7; j >= 0; --j) {
                const unsigned hv = hh[j];
                if (!done) {
                    if (acc + hv >= Krem) { T = (unsigned)(base + j); bc = hv; done = true; }
                    else acc += hv;
                }
            }
            *sT = T; *sGt = acc; *sBc = bc;
        }
    }
}
} // namespace

// (NT,4): 128-VGPR budget for the 12-float4 live set (48 VGPR) held across
// the count->scan->emit phases. Stream loop is pure load+VALU: no LDS
// atomics, no ballot/readfirstlane chains on the load-consumption path.
__global__ __launch_bounds__(NT, 4) void rtdetr_post_kernel(
    const float* __restrict__ logits,   // [B,Q,C]
    const float* __restrict__ pboxes,   // [B,Q,4] cxcywh
    const float* __restrict__ sizes,    // [B,2]   (w,h)
    float* __restrict__ out,            // [BK labels | BK*4 boxes | BK scores]
    int B)
{
    __shared__ __align__(16) unsigned long long cand[CAP];    // 8 KB
    __shared__ __align__(16) unsigned long long sorted[CAP];  // 8 KB
    __shared__ __align__(16) unsigned hist[NBB];              // 8 KB
    __shared__ __align__(16) unsigned starts[NBB];            // 8 KB
    __shared__ unsigned wsum[NW];
    __shared__ unsigned s_T, s_gt, s_bc, s_cnt;

    const int b    = blockIdx.x;
    const int tid  = threadIdx.x;
    const int lane = tid & 63;
    const float4* __restrict__ row4 = (const float4*)(logits + (size_t)b * QC);

    ((uint4*)hist)[tid] = make_uint4(0u, 0u, 0u, 0u);   // zero 2048 bins
    __syncthreads();

    // ---- Phase A: all 12 float4 upfront; masks+count only (pure VALU)
    float4 v[12];
    unsigned mk[12];
    #pragma unroll
    for (int s = 0; s < 11; ++s) v[s] = ntload4(&row4[tid + s * NT]);
    v[11] = make_float4(-1e30f, -1e30f, -1e30f, -1e30f);
    if (tid < (QC4 - 11 * NT)) v[11] = ntload4(&row4[tid + 11 * NT]);

    unsigned myCnt = 0;
    #pragma unroll
    for (int s = 0; s < 12; ++s) {
        const unsigned m = (v[s].x > T0 ? 1u : 0u) | (v[s].y > T0 ? 2u : 0u)
                         | (v[s].z > T0 ? 4u : 0u) | (v[s].w > T0 ? 8u : 0u);
        mk[s] = m;
        myCnt += (unsigned)__popc(m);
    }

    // ---- block-wide exclusive scan of per-thread counts
    unsigned total, myBase;
    {
        unsigned inc = myCnt;
        #pragma unroll
        for (int off = 1; off < 64; off <<= 1) {
            const unsigned n = __shfl_up(inc, off, 64);
            if (lane >= off) inc += n;
        }
        if (lane == 63) wsum[tid >> 6] = inc;
        __syncthreads();
        const int w = tid >> 6;
        unsigned wexcl = 0, tot = 0;
        #pragma unroll
        for (int j = 0; j < NW; ++j) {
            const unsigned sj = wsum[j];
            wexcl += (j < w) ? sj : 0u;
            tot += sj;
        }
        total  = tot;
        myBase = wexcl + inc - myCnt;
    }

    // ---- Phase B: emit candidates + hist from registers (no cursor atomics)
    {
        unsigned p = myBase;
        #pragma unroll
        for (int s = 0; s < 12; ++s) {
            unsigned m = mk[s];
            const unsigned i4 = 4u * (unsigned)(tid + s * NT);
            while (m) {
                const unsigned c = (unsigned)__builtin_ctz(m);
                m &= m - 1u;
                const float xlo = (c & 1u) ? v[s].y : v[s].x;
                const float xhi = (c & 1u) ? v[s].w : v[s].z;
                const float x   = (c & 2u) ? xhi : xlo;
                if (p < CAP) {
                    cand[p] = ((unsigned long long)mono(x) << 32) | (unsigned)(~(i4 + c));
                    atomicAdd(&hist[binOf(x)], 1u);
                }
                ++p;
            }
        }
    }
    __syncthreads();

    // ---- exactness fallback: full radix select (block-uniform, normally dead)
    if (total < (unsigned)Kk || total > (unsigned)CAP) {
        if (tid == 0) s_cnt = 0;
        unsigned prefix = 0, pbits = 0, gtAll = 0, binCnt = 0, Krem = Kk;
        do {
            __syncthreads();
            if (tid < NB) hist[tid] = 0;
            __syncthreads();
            const unsigned nb  = (32u - pbits) < 9u ? (32u - pbits) : 9u;
            const unsigned dsh = 32u - pbits - nb;
            const unsigned msk = (1u << nb) - 1u;
            for (int i = tid; i < QC4; i += NT) {
                const float4 vv = ntload4(&row4[i]);
                const unsigned kk[4] = {mono(vv.x), mono(vv.y), mono(vv.z), mono(vv.w)};
                #pragma unroll
                for (int j = 0; j < 4; ++j) {
                    const bool in = (pbits == 0u) || ((kk[j] >> (32u - pbits)) == prefix);
                    if (in) atomicAdd(&hist[(kk[j] >> dsh) & msk], 1u);
                }
            }
            __syncthreads();
            select512p(hist, Krem, &s_T, &s_gt, &s_bc, tid);
            __syncthreads();
            prefix = (prefix << nb) | s_T;
            pbits += nb;
            gtAll += s_gt; binCnt = s_bc; Krem -= s_gt;
        } while (gtAll + binCnt > CAP && pbits < 32);

        __syncthreads();
        const unsigned thrK = (pbits >= 32u) ? prefix : (prefix << (32u - pbits));
        for (int i = tid; i < QC4; i += NT) {
            const float4 vv = ntload4(&row4[i]);
            const unsigned kk[4] = {mono(vv.x), mono(vv.y), mono(vv.z), mono(vv.w)};
            #pragma unroll
            for (int j = 0; j < 4; ++j) {
                if (kk[j] >= thrK) {
                    const unsigned p = atomicAdd(&s_cnt, 1u);
                    if (p < CAP)
                        cand[p] = ((unsigned long long)kk[j] << 32) | (~(4u * (unsigned)i + (unsigned)j));
                }
            }
        }
        __syncthreads();
        ((uint4*)hist)[tid] = make_uint4(0u, 0u, 0u, 0u);  // re-zero + rebuild
        total = s_cnt;
        __syncthreads();
        const unsigned cfn = total < CAP ? total : CAP;
        for (unsigned j = tid; j < cfn; j += NT)
            atomicAdd(&hist[binOf(inv_mono((unsigned)(cand[j] >> 32)))], 1u);
        __syncthreads();
    }

    const unsigned cnt = total < CAP ? total : CAP;

    // ---- block-wide suffix scan (descending bins) -> exclusive group starts
    {
        const int m = NBB - 4 - 4 * tid;            // this thread's 4 bins
        const uint4 q = *(const uint4*)&hist[m];    // q.w is the HIGHEST bin
        const unsigned s = q.x + q.y + q.z + q.w;
        unsigned inc = s;
        #pragma unroll
        for (int off = 1; off < 64; off <<= 1) {
            const unsigned n = __shfl_up(inc, off, 64);
            if (lane >= off) inc += n;
        }
        if (lane == 63) wsum[tid >> 6] = inc;
        __syncthreads();
        const int w = tid >> 6;
        unsigned wexcl = 0;
        #pragma unroll
        for (int j = 0; j < NW; ++j) wexcl += (j < w) ? wsum[j] : 0u;
        const unsigned excl = wexcl + inc - s;      // keys in bins above q.w's bin
        const unsigned Sw = excl;
        const unsigned Sz = Sw + q.w;
        const unsigned Sy = Sz + q.z;
        const unsigned Sx = Sy + q.y;
        const uint4 st = make_uint4(Sx, Sy, Sz, Sw);
        *(uint4*)&starts[m] = st;
        *(uint4*)&hist[m]   = st;
    }
    __syncthreads();

    // ---- scatter into bin-grouped (descending) order
    for (unsigned j = tid; j < cnt; j += NT) {
        const unsigned long long kj = cand[j];
        const unsigned d = binOf(inv_mono((unsigned)(kj >> 32)));
        const unsigned p = atomicAdd(&hist[d], 1u);
        sorted[p] = kj;
    }
    __syncthreads();

    // ---- exact rank = group start + #larger within group; emit
    const float sw  = sizes[2 * b + 0];
    const float shh = sizes[2 * b + 1];
    const size_t BK = (size_t)B * Kk;

    for (unsigned p = tid; p < cnt; p += NT) {
        const unsigned long long kj = sorted[p];
        const float logit = inv_mono((unsigned)(kj >> 32));
        const unsigned d  = binOf(logit);
        const unsigned lo = starts[d];
        const unsigned hi = hist[d];                 // end after scatter
        unsigned r = lo;
        for (unsigned q = lo; q < hi; ++q)
            r += (sorted[q] > kj) ? 1u : 0u;
        if (r < (unsigned)Kk) {
            const unsigned i   = ~((unsigned)kj);    // flat idx in [0, QC)
            const unsigned q   = i / Cn;
            const unsigned lab = i - q * Cn;
            const float score  = 1.0f / (1.0f + expf(-logit));
            const float4 bx = ((const float4*)pboxes)[(size_t)b * Qn + q];
            const float x0 = (bx.x - 0.5f * bx.z) * sw;
            const float y0 = (bx.y - 0.5f * bx.w) * shh;
            const float x1 = (bx.x + 0.5f * bx.z) * sw;
            const float y1 = (bx.y + 0.5f * bx.w) * shh;
            const size_t obase = (size_t)b * Kk + r;
            out[obase] = (float)lab;                 // labels
            *(float4*)(out + BK + obase * 4) = make_float4(x0, y0, x1, y1);
            out[5 * BK + obase] = score;             // scores
        }
    }
}

extern "C" void kernel_launch(void* const* d_in, const int* in_sizes, int n_in,
                              void* d_out, int out_size, void* d_ws, size_t ws_size,
                              hipStream_t stream) {
    const float* logits = (const float*)d_in[0];
    const float* pboxes = (const float*)d_in[1];
    const float* sizes  = (const float*)d_in[2];
    float* out = (float*)d_out;
    const int B = in_sizes[2] / 2;   // orig_target_sizes is [B,2]
    hipLaunchKernelGGL(rtdetr_post_kernel, dim3(B), dim3(NT), 0, stream,
                       logits, pboxes, sizes, out, B);
}

// Round 5
// 27.201 us; speedup vs baseline: 2.2867x; 2.2867x over previous
//
#include <hip/hip_runtime.h>
#include <math.h>

namespace {
constexpr int Qn  = 300;
constexpr int Cn  = 80;
constexpr int QC  = Qn * Cn;     // 24000 per row
constexpr int QC4 = QC / 4;      // 6000 float4 per row
constexpr int Kk  = 300;         // top-k
constexpr int NT  = 512;         // 8 waves per block
constexpr int NW  = NT / 64;     // waves per block
constexpr int CAP = 1024;        // candidate buffer capacity
constexpr int NB  = 512;         // fallback radix bins
constexpr int NBB = 2048;        // counting-sort bins

// Fast-path pre-filter: logits ~ N(0,1); K-th of 24000 sits at z ~= 2.24.
// Count(logit > 2.0) ~= 546 +- 23 => P(<300) and P(>1024) are ~0.
// Exactness for ANY input preserved by the radix-select fallback.
constexpr float T0 = 2.0f;

typedef float __attribute__((ext_vector_type(4))) f32x4;

// Non-temporal streaming load: logits are use-once data; skip cache
// allocation on the read path (emits global_load_dwordx4 ... nt).
__device__ __forceinline__ float4 ntload4(const float4* __restrict__ p) {
    const f32x4 t = __builtin_nontemporal_load((const f32x4*)p);
    return make_float4(t.x, t.y, t.z, t.w);
}

__device__ __forceinline__ unsigned mono(float f) {
    // branchless order-preserving map: b ^ ((b>>31 signed) | 0x80000000)
    unsigned b = __float_as_uint(f);
    return b ^ (unsigned)(((int)b >> 31) | (int)0x80000000);
}
__device__ __forceinline__ float inv_mono(unsigned u) {
    unsigned b = (u & 0x80000000u) ? (u & 0x7fffffffu) : ~u;
    return __uint_as_float(b);
}
// Monotone logit -> bin map (bins of width 1/512 logit above T0; clamped).
// Same-bin ties are resolved exactly by the in-group 64-bit compare.
__device__ __forceinline__ unsigned binOf(float logit) {
    int d = (int)((logit - T0) * 512.0f);
    d = d < 0 ? 0 : (d > NBB - 1 ? NBB - 1 : d);
    return (unsigned)d;
}

// Wave-0 suffix-select over NB=512 plain bins (descending). Fallback only.
__device__ __forceinline__ void select512p(const unsigned* __restrict__ h,
                                           unsigned Krem, unsigned* sT,
                                           unsigned* sGt, unsigned* sBc, int tid) {
    if (tid < 64) {
        const int base = NB - 8 * (tid + 1);   // lane 0 owns the TOP 8 bins
        const uint4 qa = *(const uint4*)&h[base + 0];
        const uint4 qb = *(const uint4*)&h[base + 4];
        const unsigned hh[8] = {qa.x, qa.y, qa.z, qa.w, qb.x, qb.y, qb.z, qb.w};
        unsigned s = 0;
        #pragma unroll
        for (int j = 0; j < 8; ++j) s += hh[j];
        unsigned inc = s;
        #pragma unroll
        for (int off = 1; off < 64; off <<= 1) {
            const unsigned n = __shfl_up(inc, off, 64);
            if (tid >= off) inc += n;
        }
        const unsigned excl = inc - s;
        if (excl < Krem && Krem <= inc) {      // exactly one lane true
            unsigned acc = excl, T = 0, bc = 0;
            bool done = false;
            #pragma unroll
            for (int j = 7; j >= 0; --j) {
                const unsigned hv = hh[j];
                if (!done) {
                    if (acc + hv >= Krem) { T = (unsigned)(base + j); bc = hv; done = true; }
                    else acc += hv;
                }
            }
            *sT = T; *sGt = acc; *sBc = bc;
        }
    }
}
} // namespace

// (NT,4): 128-VGPR budget. The 12 in-flight float4 are NAMED variables and
// the per-slot masks live packed in one u64 -> every access is compile-time
// static, so nothing can be demoted to scratch (R4 lesson: VGPR_Count=28 +
// 106 MB WRITE_SIZE = the v[12]/mk[12] arrays went to local memory).
__global__ __launch_bounds__(NT, 4) void rtdetr_post_kernel(
    const float* __restrict__ logits,   // [B,Q,C]
    const float* __restrict__ pboxes,   // [B,Q,4] cxcywh
    const float* __restrict__ sizes,    // [B,2]   (w,h)
    float* __restrict__ out,            // [BK labels | BK*4 boxes | BK scores]
    int B)
{
    __shared__ __align__(16) unsigned long long cand[CAP];    // 8 KB
    __shared__ __align__(16) unsigned long long sorted[CAP];  // 8 KB
    __shared__ __align__(16) unsigned hist[NBB];              // 8 KB
    __shared__ __align__(16) unsigned starts[NBB];            // 8 KB
    __shared__ unsigned wsum[NW];
    __shared__ unsigned s_T, s_gt, s_bc, s_cnt;

    const int b    = blockIdx.x;
    const int tid  = threadIdx.x;
    const int lane = tid & 63;
    const float4* __restrict__ row4 = (const float4*)(logits + (size_t)b * QC);

    ((uint4*)hist)[tid] = make_uint4(0u, 0u, 0u, 0u);   // zero 2048 bins
    __syncthreads();

    // ---- Phase A: 12 named float4 in flight; masks packed in one u64
    float4 v0  = ntload4(&row4[tid + 0  * NT]);
    float4 v1  = ntload4(&row4[tid + 1  * NT]);
    float4 v2  = ntload4(&row4[tid + 2  * NT]);
    float4 v3  = ntload4(&row4[tid + 3  * NT]);
    float4 v4  = ntload4(&row4[tid + 4  * NT]);
    float4 v5  = ntload4(&row4[tid + 5  * NT]);
    float4 v6  = ntload4(&row4[tid + 6  * NT]);
    float4 v7  = ntload4(&row4[tid + 7  * NT]);
    float4 v8  = ntload4(&row4[tid + 8  * NT]);
    float4 v9  = ntload4(&row4[tid + 9  * NT]);
    float4 v10 = ntload4(&row4[tid + 10 * NT]);
    float4 v11 = make_float4(-1e30f, -1e30f, -1e30f, -1e30f);
    if (tid < (QC4 - 11 * NT)) v11 = ntload4(&row4[tid + 11 * NT]);

    unsigned long long mkAll = 0ull;
    unsigned myCnt = 0;
#define MASKOF(VS, SLOT) { \
    const unsigned m_ = (VS.x > T0 ? 1u : 0u) | (VS.y > T0 ? 2u : 0u) \
                      | (VS.z > T0 ? 4u : 0u) | (VS.w > T0 ? 8u : 0u); \
    mkAll |= ((unsigned long long)m_) << (4 * SLOT); \
    myCnt += (unsigned)__popc(m_); }
    MASKOF(v0, 0)  MASKOF(v1, 1)  MASKOF(v2, 2)  MASKOF(v3, 3)
    MASKOF(v4, 4)  MASKOF(v5, 5)  MASKOF(v6, 6)  MASKOF(v7, 7)
    MASKOF(v8, 8)  MASKOF(v9, 9)  MASKOF(v10, 10) MASKOF(v11, 11)
#undef MASKOF

    // ---- block-wide exclusive scan of per-thread counts
    unsigned total, myBase;
    {
        unsigned inc = myCnt;
        #pragma unroll
        for (int off = 1; off < 64; off <<= 1) {
            const unsigned n = __shfl_up(inc, off, 64);
            if (lane >= off) inc += n;
        }
        if (lane == 63) wsum[tid >> 6] = inc;
        __syncthreads();
        const int w = tid >> 6;
        unsigned wexcl = 0, tot = 0;
        #pragma unroll
        for (int j = 0; j < NW; ++j) {
            const unsigned sj = wsum[j];
            wexcl += (j < w) ? sj : 0u;
            tot += sj;
        }
        total  = tot;
        myBase = wexcl + inc - myCnt;
    }

    // ---- Phase B: emit candidates + hist (no cursor atomics, all static)
    {
        unsigned p = myBase;
#define EMIT(VS, SLOT) { \
    unsigned m_ = (unsigned)((mkAll >> (4 * SLOT)) & 0xFull); \
    const unsigned i4_ = 4u * (unsigned)(tid + SLOT * NT); \
    while (m_) { \
        const unsigned c_ = (unsigned)__builtin_ctz(m_); \
        m_ &= m_ - 1u; \
        const float xlo_ = (c_ & 1u) ? VS.y : VS.x; \
        const float xhi_ = (c_ & 1u) ? VS.w : VS.z; \
        const float x_   = (c_ & 2u) ? xhi_ : xlo_; \
        if (p < CAP) { \
            cand[p] = ((unsigned long long)mono(x_) << 32) | (unsigned)(~(i4_ + c_)); \
            atomicAdd(&hist[binOf(x_)], 1u); \
        } \
        ++p; \
    } }
        EMIT(v0, 0)  EMIT(v1, 1)  EMIT(v2, 2)  EMIT(v3, 3)
        EMIT(v4, 4)  EMIT(v5, 5)  EMIT(v6, 6)  EMIT(v7, 7)
        EMIT(v8, 8)  EMIT(v9, 9)  EMIT(v10, 10) EMIT(v11, 11)
#undef EMIT
    }
    __syncthreads();

    // ---- exactness fallback: full radix select (block-uniform, normally dead)
    if (total < (unsigned)Kk || total > (unsigned)CAP) {
        if (tid == 0) s_cnt = 0;
        unsigned prefix = 0, pbits = 0, gtAll = 0, binCnt = 0, Krem = Kk;
        do {
            __syncthreads();
            if (tid < NB) hist[tid] = 0;
            __syncthreads();
            const unsigned nb  = (32u - pbits) < 9u ? (32u - pbits) : 9u;
            const unsigned dsh = 32u - pbits - nb;
            const unsigned msk = (1u << nb) - 1u;
            for (int i = tid; i < QC4; i += NT) {
                const float4 vv = ntload4(&row4[i]);
                const unsigned kk[4] = {mono(vv.x), mono(vv.y), mono(vv.z), mono(vv.w)};
                #pragma unroll
                for (int j = 0; j < 4; ++j) {
                    const bool in = (pbits == 0u) || ((kk[j] >> (32u - pbits)) == prefix);
                    if (in) atomicAdd(&hist[(kk[j] >> dsh) & msk], 1u);
                }
            }
            __syncthreads();
            select512p(hist, Krem, &s_T, &s_gt, &s_bc, tid);
            __syncthreads();
            prefix = (prefix << nb) | s_T;
            pbits += nb;
            gtAll += s_gt; binCnt = s_bc; Krem -= s_gt;
        } while (gtAll + binCnt > CAP && pbits < 32);

        __syncthreads();
        const unsigned thrK = (pbits >= 32u) ? prefix : (prefix << (32u - pbits));
        for (int i = tid; i < QC4; i += NT) {
            const float4 vv = ntload4(&row4[i]);
            const unsigned kk[4] = {mono(vv.x), mono(vv.y), mono(vv.z), mono(vv.w)};
            #pragma unroll
            for (int j = 0; j < 4; ++j) {
                if (kk[j] >= thrK) {
                    const unsigned p = atomicAdd(&s_cnt, 1u);
                    if (p < CAP)
                        cand[p] = ((unsigned long long)kk[j] << 32) | (~(4u * (unsigned)i + (unsigned)j));
                }
            }
        }
        __syncthreads();
        ((uint4*)hist)[tid] = make_uint4(0u, 0u, 0u, 0u);  // re-zero + rebuild
        total = s_cnt;
        __syncthreads();
        const unsigned cfn = total < CAP ? total : CAP;
        for (unsigned j = tid; j < cfn; j += NT)
            atomicAdd(&hist[binOf(inv_mono((unsigned)(cand[j] >> 32)))], 1u);
        __syncthreads();
    }

    const unsigned cnt = total < CAP ? total : CAP;

    // ---- block-wide suffix scan (descending bins) -> exclusive group starts
    {
        const int m = NBB - 4 - 4 * tid;            // this thread's 4 bins
        const uint4 q = *(const uint4*)&hist[m];    // q.w is the HIGHEST bin
        const unsigned s = q.x + q.y + q.z + q.w;
        unsigned inc = s;
        #pragma unroll
        for (int off = 1; off < 64; off <<= 1) {
            const unsigned n = __shfl_up(inc, off, 64);
            if (lane >= off) inc += n;
        }
        if (lane == 63) wsum[tid >> 6] = inc;
        __syncthreads();
        const int w = tid >> 6;
        unsigned wexcl = 0;
        #pragma unroll
        for (int j = 0; j < NW; ++j) wexcl += (j < w) ? wsum[j] : 0u;
        const unsigned excl = wexcl + inc - s;      // keys in bins above q.w's bin
        const unsigned Sw = excl;
        const unsigned Sz = Sw + q.w;
        const unsigned Sy = Sz + q.z;
        const unsigned Sx = Sy + q.y;
        const uint4 st = make_uint4(Sx, Sy, Sz, Sw);
        *(uint4*)&starts[m] = st;
        *(uint4*)&hist[m]   = st;
    }
    __syncthreads();

    // ---- scatter into bin-grouped (descending) order
    for (unsigned j = tid; j < cnt; j += NT) {
        const unsigned long long kj = cand[j];
        const unsigned d = binOf(inv_mono((unsigned)(kj >> 32)));
        const unsigned p = atomicAdd(&hist[d], 1u);
        sorted[p] = kj;
    }
    __syncthreads();

    // ---- exact rank = group start + #larger within group; emit
    const float sw  = sizes[2 * b + 0];
    const float shh = sizes[2 * b + 1];
    const size_t BK = (size_t)B * Kk;

    for (unsigned p = tid; p < cnt; p += NT) {
        const unsigned long long kj = sorted[p];
        const float logit = inv_mono((unsigned)(kj >> 32));
        const unsigned d  = binOf(logit);
        const unsigned lo = starts[d];
        const unsigned hi = hist[d];                 // end after scatter
        unsigned r = lo;
        for (unsigned q = lo; q < hi; ++q)
            r += (sorted[q] > kj) ? 1u : 0u;
        if (r < (unsigned)Kk) {
            const unsigned i   = ~((unsigned)kj);    // flat idx in [0, QC)
            const unsigned q   = i / Cn;
            const unsigned lab = i - q * Cn;
            const float score  = 1.0f / (1.0f + expf(-logit));
            const float4 bx = ((const float4*)pboxes)[(size_t)b * Qn + q];
            const float x0 = (bx.x - 0.5f * bx.z) * sw;
            const float y0 = (bx.y - 0.5f * bx.w) * shh;
            const float x1 = (bx.x + 0.5f * bx.z) * sw;
            const float y1 = (bx.y + 0.5f * bx.w) * shh;
            const size_t obase = (size_t)b * Kk + r;
            out[obase] = (float)lab;                 // labels
            *(float4*)(out + BK + obase * 4) = make_float4(x0, y0, x1, y1);
            out[5 * BK + obase] = score;             // scores
        }
    }
}

extern "C" void kernel_launch(void* const* d_in, const int* in_sizes, int n_in,
                              void* d_out, int out_size, void* d_ws, size_t ws_size,
                              hipStream_t stream) {
    const float* logits = (const float*)d_in[0];
    const float* pboxes = (const float*)d_in[1];
    const float* sizes  = (const float*)d_in[2];
    float* out = (float*)d_out;
    const int B = in_sizes[2] / 2;   // orig_target_sizes is [B,2]
    hipLaunchKernelGGL(rtdetr_post_kernel, dim3(B), dim3(NT), 0, stream,
                       logits, pboxes, sizes, out, B);
}

// Round 6
// 24.126 us; speedup vs baseline: 2.5781x; 1.1275x over previous
//
#include <hip/hip_runtime.h>
#include <math.h>

namespace {
constexpr int Qn  = 300;
constexpr int Cn  = 80;
constexpr int QC  = Qn * Cn;     // 24000 per row
constexpr int QC4 = QC / 4;      // 6000 float4 per row
constexpr int Kk  = 300;         // top-k
constexpr int NT  = 512;         // 8 waves per block
constexpr int NW  = NT / 64;     // waves per block
constexpr int SEG = 128;         // per-wave candidate segment
constexpr int CAP = NW * SEG;    // 1024 total candidate capacity
constexpr int NB  = 512;         // fallback radix bins
constexpr int NBB = 2048;        // counting-sort bins

// Fast-path pre-filter: logits ~ N(0,1); K-th of 24000 sits at z ~= 2.24.
// Count(logit > 2.0) ~= 546 +- 23 per row; per wave ~70 +- 8.3 (SEG=128
// overflow is a ~7-sigma event). Exactness for ANY input preserved by the
// radix-select fallback.
constexpr float T0 = 2.0f;

typedef float __attribute__((ext_vector_type(4))) f32x4;

// Non-temporal streaming load: logits are use-once data; skip cache
// allocation on the read path (emits global_load_dwordx4 ... nt).
__device__ __forceinline__ float4 ntload4(const float4* __restrict__ p) {
    const f32x4 t = __builtin_nontemporal_load((const f32x4*)p);
    return make_float4(t.x, t.y, t.z, t.w);
}

__device__ __forceinline__ unsigned mono(float f) {
    // branchless order-preserving map: b ^ ((b>>31 signed) | 0x80000000)
    unsigned b = __float_as_uint(f);
    return b ^ (unsigned)(((int)b >> 31) | (int)0x80000000);
}
__device__ __forceinline__ float inv_mono(unsigned u) {
    unsigned b = (u & 0x80000000u) ? (u & 0x7fffffffu) : ~u;
    return __uint_as_float(b);
}
// Monotone logit -> bin map (bins of width 1/512 logit above T0; clamped).
// Same-bin ties are resolved exactly by the in-group 64-bit compare.
__device__ __forceinline__ unsigned binOf(float logit) {
    int d = (int)((logit - T0) * 512.0f);
    d = d < 0 ? 0 : (d > NBB - 1 ? NBB - 1 : d);
    return (unsigned)d;
}

__device__ __forceinline__ unsigned mbcnt64(unsigned long long m) {
    return __builtin_amdgcn_mbcnt_hi((unsigned)(m >> 32),
           __builtin_amdgcn_mbcnt_lo((unsigned)m, 0u));
}

// Wave-0 suffix-select over NB=512 plain bins (descending). Fallback only.
__device__ __forceinline__ void select512p(const unsigned* __restrict__ h,
                                           unsigned Krem, unsigned* sT,
                                           unsigned* sGt, unsigned* sBc, int tid) {
    if (tid < 64) {
        const int base = NB - 8 * (tid + 1);   // lane 0 owns the TOP 8 bins
        const uint4 qa = *(const uint4*)&h[base + 0];
        const uint4 qb = *(const uint4*)&h[base + 4];
        const unsigned hh[8] = {qa.x, qa.y, qa.z, qa.w, qb.x, qb.y, qb.z, qb.w};
        unsigned s = 0;
        #pragma unroll
        for (int j = 0; j < 8; ++j) s += hh[j];
        unsigned inc = s;
        #pragma unroll
        for (int off = 1; off < 64; off <<= 1) {
            const unsigned n = __shfl_up(inc, off, 64);
            if (tid >= off) inc += n;
        }
        const unsigned excl = inc - s;
        if (excl < Krem && Krem <= inc) {      // exactly one lane true
            unsigned acc = excl, T = 0, bc = 0;
            bool done = false;
            #pragma unroll
            for (int j = 7; j >= 0; --j) {
                const unsigned hv = hh[j];
                if (!done) {
                    if (acc + hv >= Krem) { T = (unsigned)(base + j); bc = hv; done = true; }
                    else acc += hv;
                }
            }
            *sT = T; *sGt = acc; *sBc = bc;
        }
    }
}
} // namespace

// R3 structure (best: 24.3us) with ONE change: candidate emission uses
// wave-private LDS segments + a wave-uniform register cursor. Zero LDS
// atomics / readfirstlane round-trips in the stream. Emission is per
// element-column with ALL lanes converged (ballot/popc executed by every
// lane) so wcur stays wave-uniform -- no divergent while(m) loop.
__global__ __launch_bounds__(NT, 8) void rtdetr_post_kernel(
    const float* __restrict__ logits,   // [B,Q,C]
    const float* __restrict__ pboxes,   // [B,Q,4] cxcywh
    const float* __restrict__ sizes,    // [B,2]   (w,h)
    float* __restrict__ out,            // [BK labels | BK*4 boxes | BK scores]
    int B)
{
    __shared__ __align__(16) unsigned long long cand[CAP];    // 8 KB (segmented)
    __shared__ __align__(16) unsigned long long sorted[CAP];  // 8 KB
    __shared__ __align__(16) unsigned hist[NBB];              // 8 KB
    __shared__ __align__(16) unsigned starts[NBB];            // 8 KB
    __shared__ unsigned wcnt_s[NW];
    __shared__ unsigned wsum[NW];
    __shared__ unsigned s_T, s_gt, s_bc, s_cnt;

    const int b    = blockIdx.x;
    const int tid  = threadIdx.x;
    const int lane = tid & 63;
    const int segBase = (tid >> 6) * SEG;
    const float4* __restrict__ row4 = (const float4*)(logits + (size_t)b * QC);

    ((uint4*)hist)[tid] = make_uint4(0u, 0u, 0u, 0u);   // zero 2048 bins
    __syncthreads();

    // ---- stream: R3 interleave; emission = segment write + register cursor
    unsigned wcur = 0;                 // wave-uniform (all lanes execute +=)
    {
        auto emit1 = [&](const float x, const unsigned idx) {
            const bool pass = x > T0;
            const unsigned long long act = __ballot(pass);
            if (pass) {
                const unsigned p = wcur + mbcnt64(act);
                if (p < SEG)
                    cand[segBase + p] =
                        ((unsigned long long)mono(x) << 32) | (unsigned)(~idx);
            }
            wcur += (unsigned)__popcll(act);
        };
        auto proc = [&](const float4 v, const int slot) {
            const unsigned i4 = 4u * (unsigned)(tid + slot * NT);
            emit1(v.x, i4 + 0u);
            emit1(v.y, i4 + 1u);
            emit1(v.z, i4 + 2u);
            emit1(v.w, i4 + 3u);
        };

        float4 va[4], vb[4];
        #pragma unroll
        for (int u = 0; u < 4; ++u) va[u] = ntload4(&row4[tid + u * NT]);        // slots 0..3
        #pragma unroll
        for (int u = 0; u < 4; ++u) vb[u] = ntload4(&row4[tid + (4 + u) * NT]);  // slots 4..7

        #pragma unroll
        for (int u = 0; u < 4; ++u) proc(va[u], u);
        #pragma unroll
        for (int u = 0; u < 4; ++u) {                    // slots 8..11 (11 masked)
            const int slot = 8 + u;
            if (slot < 11 || tid < (QC4 - 11 * NT)) va[u] = ntload4(&row4[tid + slot * NT]);
            else va[u] = make_float4(-1e30f, -1e30f, -1e30f, -1e30f);
        }
        #pragma unroll
        for (int u = 0; u < 4; ++u) proc(vb[u], 4 + u);
        #pragma unroll
        for (int u = 0; u < 4; ++u) proc(va[u], 8 + u);
    }
    if (lane == 0) wcnt_s[tid >> 6] = wcur;   // true per-wave event count
    __syncthreads();

    // ---- totals (static unroll; no runtime-indexed register arrays)
    unsigned total = 0;
    bool ovf = false;
    #pragma unroll
    for (int w = 0; w < NW; ++w) {
        const unsigned x = wcnt_s[w];
        total += x;
        ovf |= (x > (unsigned)SEG);
    }
    const bool fb = (total < (unsigned)Kk) || (total > (unsigned)CAP) || ovf;

    if (!fb) {
        // ---- build counting-sort hist from segments (common path)
        for (int j = tid; j < CAP; j += NT) {           // exactly 2 iters
            const int w = j >> 7, off = j & (SEG - 1);
            if ((unsigned)off < wcnt_s[w])
                atomicAdd(&hist[binOf(inv_mono((unsigned)(cand[j] >> 32)))], 1u);
        }
    } else {
        // ---- exactness fallback: full radix select (block-uniform, ~never)
        if (tid == 0) s_cnt = 0;
        unsigned prefix = 0, pbits = 0, gtAll = 0, binCnt = 0, Krem = Kk;
        do {
            __syncthreads();
            if (tid < NB) hist[tid] = 0;
            __syncthreads();
            const unsigned nb  = (32u - pbits) < 9u ? (32u - pbits) : 9u;
            const unsigned dsh = 32u - pbits - nb;
            const unsigned msk = (1u << nb) - 1u;
            for (int i = tid; i < QC4; i += NT) {
                const float4 vv = ntload4(&row4[i]);
                const unsigned kk[4] = {mono(vv.x), mono(vv.y), mono(vv.z), mono(vv.w)};
                #pragma unroll
                for (int j = 0; j < 4; ++j) {
                    const bool in = (pbits == 0u) || ((kk[j] >> (32u - pbits)) == prefix);
                    if (in) atomicAdd(&hist[(kk[j] >> dsh) & msk], 1u);
                }
            }
            __syncthreads();
            select512p(hist, Krem, &s_T, &s_gt, &s_bc, tid);
            __syncthreads();
            prefix = (prefix << nb) | s_T;
            pbits += nb;
            gtAll += s_gt; binCnt = s_bc; Krem -= s_gt;
        } while (gtAll + binCnt > CAP && pbits < 32);

        __syncthreads();
        const unsigned thrK = (pbits >= 32u) ? prefix : (prefix << (32u - pbits));
        for (int i = tid; i < QC4; i += NT) {
            const float4 vv = ntload4(&row4[i]);
            const unsigned kk[4] = {mono(vv.x), mono(vv.y), mono(vv.z), mono(vv.w)};
            #pragma unroll
            for (int j = 0; j < 4; ++j) {
                if (kk[j] >= thrK) {
                    const unsigned p = atomicAdd(&s_cnt, 1u);
                    if (p < CAP)
                        cand[p] = ((unsigned long long)kk[j] << 32) | (~(4u * (unsigned)i + (unsigned)j));
                }
            }
        }
        __syncthreads();
        ((uint4*)hist)[tid] = make_uint4(0u, 0u, 0u, 0u);  // re-zero + rebuild
        total = s_cnt;
        __syncthreads();
        const unsigned cfn = total < (unsigned)CAP ? total : (unsigned)CAP;
        for (unsigned j = tid; j < cfn; j += NT)
            atomicAdd(&hist[binOf(inv_mono((unsigned)(cand[j] >> 32)))], 1u);
        // rewrite wcnt_s so the segment-space consumers cover the
        // contiguous layout: wcnt[w] = clamp(cfn - w*SEG, 0, SEG)
        if (tid < NW) {
            const int lo = (int)cfn - tid * SEG;
            wcnt_s[tid] = (unsigned)(lo < 0 ? 0 : (lo > SEG ? SEG : lo));
        }
    }
    __syncthreads();

    const unsigned cnt = total < (unsigned)CAP ? total : (unsigned)CAP;

    // ---- block-wide suffix scan (descending bins) -> exclusive group starts
    {
        const int m = NBB - 4 - 4 * tid;            // this thread's 4 bins
        const uint4 q = *(const uint4*)&hist[m];    // q.w is the HIGHEST bin
        const unsigned s = q.x + q.y + q.z + q.w;
        unsigned inc = s;
        #pragma unroll
        for (int off = 1; off < 64; off <<= 1) {
            const unsigned n = __shfl_up(inc, off, 64);
            if (lane >= off) inc += n;
        }
        if (lane == 63) wsum[tid >> 6] = inc;
        __syncthreads();
        const int w = tid >> 6;
        unsigned wexcl = 0;
        #pragma unroll
        for (int j = 0; j < NW; ++j) wexcl += (j < w) ? wsum[j] : 0u;
        const unsigned excl = wexcl + inc - s;      // keys in bins above q.w's bin
        const unsigned Sw = excl;
        const unsigned Sz = Sw + q.w;
        const unsigned Sy = Sz + q.z;
        const unsigned Sx = Sy + q.y;
        const uint4 st = make_uint4(Sx, Sy, Sz, Sw);
        *(uint4*)&starts[m] = st;
        *(uint4*)&hist[m]   = st;
    }
    __syncthreads();

    // ---- scatter into bin-grouped (descending) order (segment space)
    for (int j = tid; j < CAP; j += NT) {           // exactly 2 iters
        const int w = j >> 7, off = j & (SEG - 1);
        if ((unsigned)off < wcnt_s[w]) {
            const unsigned long long kj = cand[j];
            const unsigned d = binOf(inv_mono((unsigned)(kj >> 32)));
            const unsigned p = atomicAdd(&hist[d], 1u);
            sorted[p] = kj;
        }
    }
    __syncthreads();

    // ---- exact rank = group start + #larger within group; emit
    const float sw  = sizes[2 * b + 0];
    const float shh = sizes[2 * b + 1];
    const size_t BK = (size_t)B * Kk;

    for (unsigned p = tid; p < cnt; p += NT) {
        const unsigned long long kj = sorted[p];
        const float logit = inv_mono((unsigned)(kj >> 32));
        const unsigned d  = binOf(logit);
        const unsigned lo = starts[d];
        const unsigned hi = hist[d];                 // end after scatter
        unsigned r = lo;
        for (unsigned q = lo; q < hi; ++q)
            r += (sorted[q] > kj) ? 1u : 0u;
        if (r < (unsigned)Kk) {
            const unsigned i   = ~((unsigned)kj);    // flat idx in [0, QC)
            const unsigned q   = i / Cn;
            const unsigned lab = i - q * Cn;
            const float score  = 1.0f / (1.0f + expf(-logit));
            const float4 bx = ((const float4*)pboxes)[(size_t)b * Qn + q];
            const float x0 = (bx.x - 0.5f * bx.z) * sw;
            const float y0 = (bx.y - 0.5f * bx.w) * shh;
            const float x1 = (bx.x + 0.5f * bx.z) * sw;
            const float y1 = (bx.y + 0.5f * bx.w) * shh;
            const size_t obase = (size_t)b * Kk + r;
            out[obase] = (float)lab;                 // labels
            *(float4*)(out + BK + obase * 4) = make_float4(x0, y0, x1, y1);
            out[5 * BK + obase] = score;             // scores
        }
    }
}

extern "C" void kernel_launch(void* const* d_in, const int* in_sizes, int n_in,
                              void* d_out, int out_size, void* d_ws, size_t ws_size,
                              hipStream_t stream) {
    const float* logits = (const float*)d_in[0];
    const float* pboxes = (const float*)d_in[1];
    const float* sizes  = (const float*)d_in[2];
    float* out = (float*)d_out;
    const int B = in_sizes[2] / 2;   // orig_target_sizes is [B,2]
    hipLaunchKernelGGL(rtdetr_post_kernel, dim3(B), dim3(NT), 0, stream,
                       logits, pboxes, sizes, out, B);
}